// Round 9
// baseline (213.887 us; speedup 1.0000x reference)
//
#include <hip/hip_runtime.h>

#define N_NODES 100000
#define N_EDGES 3200000

// ---- bucket parameters -----------------------------------------------------
#define BSH   8                   // log2(nodes per bucket)
#define BSZ   256                 // nodes per bucket
#define NB    391                 // ceil(N_NODES / BSZ)
#define CAP   12288               // bucket capacity (payload ~8184 + pad ~2800, 11 sigma margin)
#define CHUNK 4096                // edges per binning block
#define BINT  512                 // threads per binning block
#define EPT   (CHUNK / BINT)      // 8 edges per thread
#define GT    512                 // threads per gather block
#define TRASH 256u                // local slot 256 = discard

// ---------------------------------------------------------------------------
// Algebra (x is [N,1]):
//   p[u]   = dinv[u] * x[u]
//   s[v]   = dinv[v] * (sum_in p[u] + dinv[v]*x[v])
//   t[v]   = relu(s[v]*W1 + b1) @ W2          (2-vector)
//   q[u]   = dinv[u] * t[u]
//   out[v] = dinv[v] * (sum_in q[u] + dinv[v]*t[v]) + b2
//
// R4: device f32 atomics are memory-side (32B txn each, ~20 G/s) -> gather.
// R6: scattered 4B binning writes caused 5x write amp (65-74 MB HBM, lines
//     shared across XCDs). Fix: block-local LDS counting sort + 32B-aligned
//     padded segment copy-out -> full-sector single-writer stores.
// Entry format: (src << 9) | local, local in [0,255] real, 256 = TRASH pad.
// ---------------------------------------------------------------------------

__global__ void k0_zero(unsigned* __restrict__ cursor) {
    int i = blockIdx.x * blockDim.x + threadIdx.x;
    if (i < NB) cursor[i] = 0u;
}

__global__ __launch_bounds__(BINT) void
k1_bin(const int* __restrict__ src, const int* __restrict__ dst,
       unsigned* __restrict__ cursor, unsigned* __restrict__ binned, int ne) {
    __shared__ unsigned hist[NB];      // per-bucket count (rank source)
    __shared__ unsigned basel[NB];     // exclusive prefix into sorted[]
    __shared__ unsigned gbase[NB];     // global segment base per bucket
    __shared__ unsigned pcnt[NB];      // padded count per bucket
    __shared__ unsigned sorted[CHUNK]; // bucket-sorted entries
    __shared__ unsigned scan[BINT];    // scan workspace
    const int tid = threadIdx.x;
    const int b0  = blockIdx.x * CHUNK;
    const int end = min(b0 + CHUNK, ne);

    for (int i = tid; i < NB; i += BINT) hist[i] = 0u;
    __syncthreads();

    // read edges once, take rank within (block, bucket)
    unsigned ent[EPT], ebr[EPT];
#pragma unroll
    for (int k = 0; k < EPT; ++k) {
        int i = b0 + tid + k * BINT;
        ent[k] = 0xFFFFFFFFu;
        if (i < end) {
            unsigned v = (unsigned)dst[i];
            unsigned u = (unsigned)src[i];
            unsigned b = v >> BSH;
            unsigned r = atomicAdd(&hist[b], 1u);
            ent[k] = (u << 9) | (v & (BSZ - 1u));
            ebr[k] = (b << 16) | r;            // b<391 (9b), r<4096 (13b)
        }
    }
    __syncthreads();

    // exclusive block scan of hist -> basel (NB=391 <= BINT=512)
    unsigned v0 = (tid < NB) ? hist[tid] : 0u;
    scan[tid] = v0;
    __syncthreads();
    for (int off = 1; off < BINT; off <<= 1) {
        unsigned mine = scan[tid];
        unsigned add  = (tid >= off) ? scan[tid - off] : 0u;
        __syncthreads();
        scan[tid] = mine + add;
        __syncthreads();
    }
    if (tid < NB) basel[tid] = scan[tid] - v0;
    __syncthreads();

    // place into LDS sorted buffer
#pragma unroll
    for (int k = 0; k < EPT; ++k) {
        if (ent[k] != 0xFFFFFFFFu)
            sorted[basel[ebr[k] >> 16] + (ebr[k] & 0xFFFFu)] = ent[k];
    }

    // reserve 8-aligned (32 B) global segments
    if (tid < NB) {
        unsigned c = hist[tid];
        unsigned p = (c + 7u) & ~7u;
        pcnt[tid]  = p;
        gbase[tid] = p ? atomicAdd(&cursor[tid], p) : 0u;
    }
    __syncthreads();

    // copy out: wave w handles buckets w, w+8, ... (full-sector stores)
    const int wave = tid >> 6, lane = tid & 63;
    for (int b = wave; b < NB; b += BINT / 64) {
        unsigned c = hist[b], p = pcnt[b], gb = gbase[b], lb = basel[b];
        if (p == 0u || gb + p > CAP) continue;   // overflow guard (never real)
        unsigned* dstp = binned + (size_t)b * CAP + gb;
        for (unsigned j = lane; j < p; j += 64)
            dstp[j] = (j < c) ? sorted[lb + j] : TRASH;
    }
}

// Per-bucket degree count (LDS) -> dinv, p = dinv*x.
__global__ __launch_bounds__(GT) void
k2_deg(const unsigned* __restrict__ binned, const unsigned* __restrict__ cursor,
       const float* __restrict__ x, float* __restrict__ dinv, float* __restrict__ p) {
    __shared__ unsigned cnt[BSZ + 1];
    const int b = blockIdx.x, tid = threadIdx.x;
    if (tid <= BSZ) cnt[tid] = 0u;
    __syncthreads();
    unsigned m = cursor[b]; if (m > CAP) m = 0u;   // replay-safe
    const unsigned* eb = binned + (size_t)b * CAP;
#pragma unroll 4
    for (unsigned j = tid; j < m; j += GT)
        atomicAdd(&cnt[min(eb[j] & 511u, TRASH)], 1u);
    __syncthreads();
    int g = b * BSZ + tid;
    if (tid < BSZ && g < N_NODES) {
        float di = rsqrtf(1.0f + (float)cnt[tid]);  // +1 self-loop
        dinv[g] = di;
        p[g] = di * x[g];
    }
}

// Per-bucket gather of p -> s, fused tiny MLP -> tval, q.
__global__ __launch_bounds__(GT) void
k3_gather_s(const unsigned* __restrict__ binned, const unsigned* __restrict__ cursor,
            const float* __restrict__ x, const float* __restrict__ dinv,
            const float* __restrict__ p,
            const float* __restrict__ W1, const float* __restrict__ b1,
            const float* __restrict__ W2,
            float* __restrict__ tval, float* __restrict__ q) {
    __shared__ float acc[BSZ + 1];
    const int b = blockIdx.x, tid = threadIdx.x;
    if (tid <= BSZ) acc[tid] = 0.0f;
    __syncthreads();
    unsigned m = cursor[b]; if (m > CAP) m = 0u;   // replay-safe
    const unsigned* eb = binned + (size_t)b * CAP;
#pragma unroll 4
    for (unsigned j = tid; j < m; j += GT) {
        unsigned e = eb[j];
        unsigned u = min(e >> 9, (unsigned)(N_NODES - 1));
        atomicAdd(&acc[min(e & 511u, TRASH)], p[u]);  // LDS f32 atomic
    }
    __syncthreads();
    int g = b * BSZ + tid;
    if (tid < BSZ && g < N_NODES) {
        float di = dinv[g];
        float s = di * (acc[tid] + di * x[g]);
        float t0 = 0.0f, t1 = 0.0f;
#pragma unroll
        for (int k = 0; k < 16; ++k) {
            float h = fmaxf(fmaf(s, W1[k], b1[k]), 0.0f);
            t0 = fmaf(h, W2[2 * k], t0);
            t1 = fmaf(h, W2[2 * k + 1], t1);
        }
        tval[2 * g]     = t0;
        tval[2 * g + 1] = t1;
        q[2 * g]     = di * t0;
        q[2 * g + 1] = di * t1;
    }
}

// Per-bucket gather of q -> out.
__global__ __launch_bounds__(GT) void
k4_gather_out(const unsigned* __restrict__ binned, const unsigned* __restrict__ cursor,
              const float* __restrict__ dinv, const float* __restrict__ tval,
              const float* __restrict__ q, const float* __restrict__ b2,
              float* __restrict__ out) {
    __shared__ float a0[BSZ + 1], a1[BSZ + 1];
    const int b = blockIdx.x, tid = threadIdx.x;
    if (tid <= BSZ) { a0[tid] = 0.0f; a1[tid] = 0.0f; }
    __syncthreads();
    unsigned m = cursor[b]; if (m > CAP) m = 0u;   // replay-safe
    const unsigned* eb = binned + (size_t)b * CAP;
    const float2* __restrict__ q2 = (const float2*)q;
#pragma unroll 4
    for (unsigned j = tid; j < m; j += GT) {
        unsigned e = eb[j];
        unsigned u = min(e >> 9, (unsigned)(N_NODES - 1));
        float2 qq = q2[u];
        unsigned l = min(e & 511u, TRASH);
        atomicAdd(&a0[l], qq.x);
        atomicAdd(&a1[l], qq.y);
    }
    __syncthreads();
    int g = b * BSZ + tid;
    if (tid < BSZ && g < N_NODES) {
        float di = dinv[g];
        float d2 = di * di;
        float2 o;
        o.x = fmaf(di, a0[tid], fmaf(d2, tval[2 * g],     b2[0]));
        o.y = fmaf(di, a1[tid], fmaf(d2, tval[2 * g + 1], b2[1]));
        ((float2*)out)[g] = o;
    }
}

// ---- legacy atomic-scatter path (fallback if ws too small) -----------------
__global__ void k_init_deg(unsigned* __restrict__ degc, int n) {
    int i = blockIdx.x * blockDim.x + threadIdx.x;
    if (i < n) degc[i] = 1u;
}
__global__ void k_count_deg(const int* __restrict__ dst, unsigned* __restrict__ degc, int ne) {
    int stride = gridDim.x * blockDim.x;
    for (int i = blockIdx.x * blockDim.x + threadIdx.x; i < ne; i += stride)
        atomicAdd(&degc[dst[i]], 1u);
}
__global__ void k_dinv_selfloop(const float* __restrict__ x, const unsigned* __restrict__ degc,
                                float* __restrict__ dinv, float* __restrict__ s, int n) {
    int i = blockIdx.x * blockDim.x + threadIdx.x;
    if (i < n) {
        float di = rsqrtf((float)degc[i]);
        dinv[i] = di;
        s[i] = di * di * x[i];
    }
}
__global__ void k_scatter_s(const int* __restrict__ src, const int* __restrict__ dst,
                            const float* __restrict__ x, const float* __restrict__ dinv,
                            float* __restrict__ s, int ne) {
    int stride = gridDim.x * blockDim.x;
    for (int i = blockIdx.x * blockDim.x + threadIdx.x; i < ne; i += stride) {
        int u = src[i], v = dst[i];
        unsafeAtomicAdd(&s[v], dinv[u] * dinv[v] * x[u]);
    }
}
__global__ void k_node_g(const float* __restrict__ s, const float* __restrict__ dinv,
                         const float* __restrict__ W1, const float* __restrict__ b1,
                         const float* __restrict__ W2, const float* __restrict__ b2,
                         float* __restrict__ t, float* __restrict__ out, int n) {
    int i = blockIdx.x * blockDim.x + threadIdx.x;
    if (i < n) {
        float si = s[i];
        float t0 = 0.0f, t1 = 0.0f;
#pragma unroll
        for (int k = 0; k < 16; ++k) {
            float h = fmaxf(fmaf(si, W1[k], b1[k]), 0.0f);
            t0 = fmaf(h, W2[2 * k], t0);
            t1 = fmaf(h, W2[2 * k + 1], t1);
        }
        t[2 * i] = t0; t[2 * i + 1] = t1;
        float d2 = dinv[i] * dinv[i];
        out[2 * i]     = fmaf(d2, t0, b2[0]);
        out[2 * i + 1] = fmaf(d2, t1, b2[1]);
    }
}
__global__ void k_scatter_out(const int* __restrict__ src, const int* __restrict__ dst,
                              const float* __restrict__ dinv, const float* __restrict__ t,
                              float* __restrict__ out, int ne) {
    int stride = gridDim.x * blockDim.x;
    const float2* __restrict__ t2 = (const float2*)t;
    for (int i = blockIdx.x * blockDim.x + threadIdx.x; i < ne; i += stride) {
        int u = src[i], v = dst[i];
        float nrm = dinv[u] * dinv[v];
        float2 tu = t2[u];
        unsafeAtomicAdd(&out[2 * v],     nrm * tu.x);
        unsafeAtomicAdd(&out[2 * v + 1], nrm * tu.y);
    }
}

extern "C" void kernel_launch(void* const* d_in, const int* in_sizes, int n_in,
                              void* d_out, int out_size, void* d_ws, size_t ws_size,
                              hipStream_t stream) {
    const float* x  = (const float*)d_in[0];
    const int*   ei = (const int*)d_in[1];   // int32 [2, E]
    const float* W1 = (const float*)d_in[2];
    const float* b1 = (const float*)d_in[3];
    const float* W2 = (const float*)d_in[4];
    const float* b2 = (const float*)d_in[5];
    float*       out = (float*)d_out;

    const int* src = ei;
    const int* dst = ei + N_EDGES;

    // ws layout (4B units): cursor[512] | dinv[N] | p[N] | tval[2N] | q[2N] | binned[NB*CAP]
    float* base = (float*)d_ws;
    unsigned* cursor = (unsigned*)d_ws;
    float* dinv = base + 512;
    float* p    = base + 512 + N_NODES;
    float* tval = base + 512 + 2 * N_NODES;
    float* q    = base + 512 + 4 * N_NODES;
    unsigned* binned = (unsigned*)(base + 512 + 6 * N_NODES);
    const size_t NEEDED = ((size_t)512 + 6 * N_NODES + (size_t)NB * CAP) * 4;

    if (ws_size >= NEEDED) {
        const int nbin_blocks = (N_EDGES + CHUNK - 1) / CHUNK;  // 782
        k0_zero<<<2, 256, 0, stream>>>(cursor);
        k1_bin<<<nbin_blocks, BINT, 0, stream>>>(src, dst, cursor, binned, N_EDGES);
        k2_deg<<<NB, GT, 0, stream>>>(binned, cursor, x, dinv, p);
        k3_gather_s<<<NB, GT, 0, stream>>>(binned, cursor, x, dinv, p, W1, b1, W2, tval, q);
        k4_gather_out<<<NB, GT, 0, stream>>>(binned, cursor, dinv, tval, q, b2, out);
    } else {
        // legacy atomic-scatter path
        unsigned* degc = (unsigned*)d_ws;
        float* ldinv = base + N_NODES;
        float* s     = base + 2 * N_NODES;
        float* t     = base + 3 * N_NODES;
        const int BLK = 256;
        const int node_grid = (N_NODES + BLK - 1) / BLK;
        const int edge_grid = 2048;
        k_init_deg<<<node_grid, BLK, 0, stream>>>(degc, N_NODES);
        k_count_deg<<<edge_grid, BLK, 0, stream>>>(dst, degc, N_EDGES);
        k_dinv_selfloop<<<node_grid, BLK, 0, stream>>>(x, degc, ldinv, s, N_NODES);
        k_scatter_s<<<edge_grid, BLK, 0, stream>>>(src, dst, x, ldinv, s, N_EDGES);
        k_node_g<<<node_grid, BLK, 0, stream>>>(s, ldinv, W1, b1, W2, b2, t, out, N_NODES);
        k_scatter_out<<<edge_grid, BLK, 0, stream>>>(src, dst, ldinv, t, out, N_EDGES);
    }
}

// Round 10
// 187.910 us; speedup vs baseline: 1.1382x; 1.1382x over previous
//
#include <hip/hip_runtime.h>

#define N_NODES 100000
#define N_EDGES 3200000

// ---- bucket parameters -----------------------------------------------------
#define BSH   8                    // log2(nodes per bucket)
#define BSZ   256                  // nodes per bucket
#define NB    391                  // ceil(N_NODES / BSZ)
#define CAP   10560                // per-bucket capacity (payload 8192+-90*8sig + pad ~1650)
#define CHUNK 8192                 // edges per binning block
#define BINT  1024                 // threads per binning block
#define EPT   (CHUNK / BINT)       // 8 edges per thread
#define GT    512                  // threads per gather-slice block
#define SPLIT 4                    // slices per bucket
#define TRASH 256u                 // local slot 256 = discard

// ---------------------------------------------------------------------------
// Algebra (x is [N,1]):
//   p[u]   = dinv[u] * x[u]
//   s[v]   = dinv[v] * (sum_in p[u] + dinv[v]*x[v])
//   t[v]   = relu(s[v]*W1 + b1) @ W2          (2-vector)
//   out[v] = dinv[v] * (sum_in dinv[u]*t[u] + dinv[v]*t[v]) + b2
//
// R4: device f32 atomics are memory-side (32B txn, ~20 G/s) -> gather.
// R6: 4B scattered binning writes -> 5x write amp -> LDS counting sort +
//     aligned segment copy-out.
// R9: gathers were parallelism-starved (NB=391 blocks = 1.5/CU; k4=64us at
//     0.8MB traffic) and 35% pad-inflated. Fix: 4-way slice split with
//     contiguous partial writes + merge kernels; CHUNK 8192 halves pad.
// Entry format: (src << 9) | local, local in [0,255] real, 256 = TRASH pad.
// ---------------------------------------------------------------------------

__global__ void k0_zero(unsigned* __restrict__ cursor) {
    int i = blockIdx.x * blockDim.x + threadIdx.x;
    if (i < NB) cursor[i] = 0u;
}

__global__ __launch_bounds__(BINT) void
k1_bin(const int* __restrict__ src, const int* __restrict__ dst,
       unsigned* __restrict__ cursor, unsigned* __restrict__ binned, int ne) {
    __shared__ unsigned hist[NB];      // per-bucket count (rank source)
    __shared__ unsigned basel[NB];     // exclusive prefix into sorted[]
    __shared__ unsigned gbase[NB];     // global segment base per bucket
    __shared__ unsigned pcnt[NB];      // padded count per bucket
    __shared__ unsigned sorted[CHUNK]; // bucket-sorted entries
    __shared__ unsigned scan[BINT];    // scan workspace
    const int tid = threadIdx.x;
    const int b0  = blockIdx.x * CHUNK;
    const int end = min(b0 + CHUNK, ne);

    for (int i = tid; i < NB; i += BINT) hist[i] = 0u;
    __syncthreads();

    // read edges once, take rank within (block, bucket)
    unsigned ent[EPT], ebr[EPT];
#pragma unroll
    for (int k = 0; k < EPT; ++k) {
        int i = b0 + tid + k * BINT;
        ent[k] = 0xFFFFFFFFu;
        if (i < end) {
            unsigned v = (unsigned)dst[i];
            unsigned u = (unsigned)src[i];
            unsigned b = v >> BSH;
            unsigned r = atomicAdd(&hist[b], 1u);
            ent[k] = (u << 9) | (v & (BSZ - 1u));
            ebr[k] = (b << 16) | r;            // b<391 (9b), r<8192 (13b)
        }
    }
    __syncthreads();

    // exclusive block scan of hist -> basel (NB=391 <= BINT)
    unsigned v0 = (tid < NB) ? hist[tid] : 0u;
    scan[tid] = v0;
    __syncthreads();
    for (int off = 1; off < BINT; off <<= 1) {
        unsigned mine = scan[tid];
        unsigned add  = (tid >= off) ? scan[tid - off] : 0u;
        __syncthreads();
        scan[tid] = mine + add;
        __syncthreads();
    }
    if (tid < NB) basel[tid] = scan[tid] - v0;
    __syncthreads();

    // place into LDS sorted buffer
#pragma unroll
    for (int k = 0; k < EPT; ++k) {
        if (ent[k] != 0xFFFFFFFFu)
            sorted[basel[ebr[k] >> 16] + (ebr[k] & 0xFFFFu)] = ent[k];
    }

    // reserve 8-aligned (32 B) global segments
    if (tid < NB) {
        unsigned c = hist[tid];
        unsigned p = (c + 7u) & ~7u;
        pcnt[tid]  = p;
        gbase[tid] = p ? atomicAdd(&cursor[tid], p) : 0u;
    }
    __syncthreads();

    // copy out: wave w handles buckets w, w+16, ... (full-sector stores)
    const int wave = tid >> 6, lane = tid & 63;
    for (int b = wave; b < NB; b += BINT / 64) {
        unsigned c = hist[b], p = pcnt[b], gb = gbase[b], lb = basel[b];
        if (p == 0u || gb + p > CAP) continue;   // overflow guard (never real)
        unsigned* dstp = binned + (size_t)b * CAP + gb;
        for (unsigned j = lane; j < p; j += 64)
            dstp[j] = (j < c) ? sorted[lb + j] : TRASH;
    }
}

// ---- slice gather kernels: grid = NB*SPLIT, contiguous partial writes ------

// degree counts per slice -> partc[b][slice][256]
__global__ __launch_bounds__(GT) void
k2a_deg(const unsigned* __restrict__ binned, const unsigned* __restrict__ cursor,
        unsigned* __restrict__ partc) {
    __shared__ unsigned cnt[BSZ + 1];
    const int b = blockIdx.x >> 2, sl = blockIdx.x & 3, tid = threadIdx.x;
    if (tid <= BSZ) cnt[tid] = 0u;
    __syncthreads();
    unsigned m = cursor[b]; if (m > CAP) m = 0u;   // replay-safe
    const unsigned* eb = binned + (size_t)b * CAP;
    for (unsigned j = sl * GT + tid; j < m; j += GT * SPLIT)
        atomicAdd(&cnt[min(eb[j] & 511u, TRASH)], 1u);
    __syncthreads();
    if (tid < BSZ) partc[((size_t)b * SPLIT + sl) * BSZ + tid] = cnt[tid];
}

// merge counts -> dinv, p
__global__ __launch_bounds__(BSZ) void
k2b_dinv(const unsigned* __restrict__ partc, const float* __restrict__ x,
         float* __restrict__ dinv, float* __restrict__ p) {
    const int b = blockIdx.x, tid = threadIdx.x;
    int g = b * BSZ + tid;
    if (g < N_NODES) {
        const unsigned* pc = partc + (size_t)b * SPLIT * BSZ + tid;
        unsigned deg = 1u + pc[0] + pc[BSZ] + pc[2 * BSZ] + pc[3 * BSZ];
        float di = rsqrtf((float)deg);
        dinv[g] = di;
        p[g] = di * x[g];
    }
}

// layer-1 sums per slice -> parts[b][slice][256]
__global__ __launch_bounds__(GT) void
k3a_sum(const unsigned* __restrict__ binned, const unsigned* __restrict__ cursor,
        const float* __restrict__ p, float* __restrict__ parts) {
    __shared__ float acc[BSZ + 1];
    const int b = blockIdx.x >> 2, sl = blockIdx.x & 3, tid = threadIdx.x;
    if (tid <= BSZ) acc[tid] = 0.0f;
    __syncthreads();
    unsigned m = cursor[b]; if (m > CAP) m = 0u;   // replay-safe
    const unsigned* eb = binned + (size_t)b * CAP;
    for (unsigned j = sl * GT + tid; j < m; j += GT * SPLIT) {
        unsigned e = eb[j];
        unsigned u = min(e >> 9, (unsigned)(N_NODES - 1));
        atomicAdd(&acc[min(e & 511u, TRASH)], p[u]);   // LDS f32 atomic
    }
    __syncthreads();
    if (tid < BSZ) parts[((size_t)b * SPLIT + sl) * BSZ + tid] = acc[tid];
}

// merge sums -> s -> tiny MLP -> tval
__global__ __launch_bounds__(BSZ) void
k3b_mlp(const float* __restrict__ parts, const float* __restrict__ x,
        const float* __restrict__ dinv,
        const float* __restrict__ W1, const float* __restrict__ b1,
        const float* __restrict__ W2, float* __restrict__ tval) {
    const int b = blockIdx.x, tid = threadIdx.x;
    int g = b * BSZ + tid;
    if (g < N_NODES) {
        const float* ps = parts + (size_t)b * SPLIT * BSZ + tid;
        float sum = ps[0] + ps[BSZ] + ps[2 * BSZ] + ps[3 * BSZ];
        float di = dinv[g];
        float s = di * (sum + di * x[g]);
        float t0 = 0.0f, t1 = 0.0f;
#pragma unroll
        for (int k = 0; k < 16; ++k) {
            float h = fmaxf(fmaf(s, W1[k], b1[k]), 0.0f);
            t0 = fmaf(h, W2[2 * k], t0);
            t1 = fmaf(h, W2[2 * k + 1], t1);
        }
        tval[2 * g]     = t0;
        tval[2 * g + 1] = t1;
    }
}

// layer-2 sums per slice -> (part0, part1)[b][slice][256]
__global__ __launch_bounds__(GT) void
k4a_sum(const unsigned* __restrict__ binned, const unsigned* __restrict__ cursor,
        const float* __restrict__ dinv, const float* __restrict__ tval,
        float* __restrict__ part0, float* __restrict__ part1) {
    __shared__ float a0[BSZ + 1], a1[BSZ + 1];
    const int b = blockIdx.x >> 2, sl = blockIdx.x & 3, tid = threadIdx.x;
    if (tid <= BSZ) { a0[tid] = 0.0f; a1[tid] = 0.0f; }
    __syncthreads();
    unsigned m = cursor[b]; if (m > CAP) m = 0u;   // replay-safe
    const unsigned* eb = binned + (size_t)b * CAP;
    const float2* __restrict__ t2 = (const float2*)tval;
    for (unsigned j = sl * GT + tid; j < m; j += GT * SPLIT) {
        unsigned e = eb[j];
        unsigned u = min(e >> 9, (unsigned)(N_NODES - 1));
        float du = dinv[u];
        float2 tu = t2[u];
        unsigned l = min(e & 511u, TRASH);
        atomicAdd(&a0[l], du * tu.x);
        atomicAdd(&a1[l], du * tu.y);
    }
    __syncthreads();
    if (tid < BSZ) {
        size_t o = ((size_t)b * SPLIT + sl) * BSZ + tid;
        part0[o] = a0[tid];
        part1[o] = a1[tid];
    }
}

// merge layer-2 sums -> out
__global__ __launch_bounds__(BSZ) void
k4b_out(const float* __restrict__ part0, const float* __restrict__ part1,
        const float* __restrict__ dinv, const float* __restrict__ tval,
        const float* __restrict__ b2, float* __restrict__ out) {
    const int b = blockIdx.x, tid = threadIdx.x;
    int g = b * BSZ + tid;
    if (g < N_NODES) {
        const float* p0 = part0 + (size_t)b * SPLIT * BSZ + tid;
        const float* p1 = part1 + (size_t)b * SPLIT * BSZ + tid;
        float o0 = p0[0] + p0[BSZ] + p0[2 * BSZ] + p0[3 * BSZ];
        float o1 = p1[0] + p1[BSZ] + p1[2 * BSZ] + p1[3 * BSZ];
        float di = dinv[g], d2 = di * di;
        float2 o;
        o.x = fmaf(di, o0, fmaf(d2, tval[2 * g],     b2[0]));
        o.y = fmaf(di, o1, fmaf(d2, tval[2 * g + 1], b2[1]));
        ((float2*)out)[g] = o;
    }
}

// ---- legacy atomic-scatter path (fallback if ws too small) -----------------
__global__ void k_init_deg(unsigned* __restrict__ degc, int n) {
    int i = blockIdx.x * blockDim.x + threadIdx.x;
    if (i < n) degc[i] = 1u;
}
__global__ void k_count_deg(const int* __restrict__ dst, unsigned* __restrict__ degc, int ne) {
    int stride = gridDim.x * blockDim.x;
    for (int i = blockIdx.x * blockDim.x + threadIdx.x; i < ne; i += stride)
        atomicAdd(&degc[dst[i]], 1u);
}
__global__ void k_dinv_selfloop(const float* __restrict__ x, const unsigned* __restrict__ degc,
                                float* __restrict__ dinv, float* __restrict__ s, int n) {
    int i = blockIdx.x * blockDim.x + threadIdx.x;
    if (i < n) {
        float di = rsqrtf((float)degc[i]);
        dinv[i] = di;
        s[i] = di * di * x[i];
    }
}
__global__ void k_scatter_s(const int* __restrict__ src, const int* __restrict__ dst,
                            const float* __restrict__ x, const float* __restrict__ dinv,
                            float* __restrict__ s, int ne) {
    int stride = gridDim.x * blockDim.x;
    for (int i = blockIdx.x * blockDim.x + threadIdx.x; i < ne; i += stride) {
        int u = src[i], v = dst[i];
        unsafeAtomicAdd(&s[v], dinv[u] * dinv[v] * x[u]);
    }
}
__global__ void k_node_g(const float* __restrict__ s, const float* __restrict__ dinv,
                         const float* __restrict__ W1, const float* __restrict__ b1,
                         const float* __restrict__ W2, const float* __restrict__ b2,
                         float* __restrict__ t, float* __restrict__ out, int n) {
    int i = blockIdx.x * blockDim.x + threadIdx.x;
    if (i < n) {
        float si = s[i];
        float t0 = 0.0f, t1 = 0.0f;
#pragma unroll
        for (int k = 0; k < 16; ++k) {
            float h = fmaxf(fmaf(si, W1[k], b1[k]), 0.0f);
            t0 = fmaf(h, W2[2 * k], t0);
            t1 = fmaf(h, W2[2 * k + 1], t1);
        }
        t[2 * i] = t0; t[2 * i + 1] = t1;
        float d2 = dinv[i] * dinv[i];
        out[2 * i]     = fmaf(d2, t0, b2[0]);
        out[2 * i + 1] = fmaf(d2, t1, b2[1]);
    }
}
__global__ void k_scatter_out(const int* __restrict__ src, const int* __restrict__ dst,
                              const float* __restrict__ dinv, const float* __restrict__ t,
                              float* __restrict__ out, int ne) {
    int stride = gridDim.x * blockDim.x;
    const float2* __restrict__ t2 = (const float2*)t;
    for (int i = blockIdx.x * blockDim.x + threadIdx.x; i < ne; i += stride) {
        int u = src[i], v = dst[i];
        float nrm = dinv[u] * dinv[v];
        float2 tu = t2[u];
        unsafeAtomicAdd(&out[2 * v],     nrm * tu.x);
        unsafeAtomicAdd(&out[2 * v + 1], nrm * tu.y);
    }
}

extern "C" void kernel_launch(void* const* d_in, const int* in_sizes, int n_in,
                              void* d_out, int out_size, void* d_ws, size_t ws_size,
                              hipStream_t stream) {
    const float* x  = (const float*)d_in[0];
    const int*   ei = (const int*)d_in[1];   // int32 [2, E]
    const float* W1 = (const float*)d_in[2];
    const float* b1 = (const float*)d_in[3];
    const float* W2 = (const float*)d_in[4];
    const float* b2 = (const float*)d_in[5];
    float*       out = (float*)d_out;

    const int* src = ei;
    const int* dst = ei + N_EDGES;

    // ws layout (4B units):
    // cursor[512] | dinv[N] | p[N] | tval[2N] | bufA[NB*4*256] | bufB[NB*4*256] | binned[NB*CAP]
    float* base = (float*)d_ws;
    unsigned* cursor = (unsigned*)d_ws;
    float* dinv = base + 512;
    float* p    = base + 512 + N_NODES;
    float* tval = base + 512 + 2 * N_NODES;
    float* bufA = base + 512 + 4 * N_NODES;                      // 400384 floats
    float* bufB = bufA + (size_t)NB * SPLIT * BSZ;
    unsigned* binned = (unsigned*)(bufB + (size_t)NB * SPLIT * BSZ);
    const size_t NEEDED = ((size_t)512 + 4 * N_NODES + 2 * (size_t)NB * SPLIT * BSZ
                           + (size_t)NB * CAP) * 4;              // ~21.3 MB

    if (ws_size >= NEEDED) {
        const int nbin_blocks = (N_EDGES + CHUNK - 1) / CHUNK;   // 391
        k0_zero<<<2, 256, 0, stream>>>(cursor);
        k1_bin<<<nbin_blocks, BINT, 0, stream>>>(src, dst, cursor, binned, N_EDGES);
        k2a_deg<<<NB * SPLIT, GT, 0, stream>>>(binned, cursor, (unsigned*)bufA);
        k2b_dinv<<<NB, BSZ, 0, stream>>>((unsigned*)bufA, x, dinv, p);
        k3a_sum<<<NB * SPLIT, GT, 0, stream>>>(binned, cursor, p, bufA);
        k3b_mlp<<<NB, BSZ, 0, stream>>>(bufA, x, dinv, W1, b1, W2, tval);
        k4a_sum<<<NB * SPLIT, GT, 0, stream>>>(binned, cursor, dinv, tval, bufA, bufB);
        k4b_out<<<NB, BSZ, 0, stream>>>(bufA, bufB, dinv, tval, b2, out);
    } else {
        // legacy atomic-scatter path
        unsigned* degc = (unsigned*)d_ws;
        float* ldinv = base + N_NODES;
        float* s     = base + 2 * N_NODES;
        float* t     = base + 3 * N_NODES;
        const int BLK = 256;
        const int node_grid = (N_NODES + BLK - 1) / BLK;
        const int edge_grid = 2048;
        k_init_deg<<<node_grid, BLK, 0, stream>>>(degc, N_NODES);
        k_count_deg<<<edge_grid, BLK, 0, stream>>>(dst, degc, N_EDGES);
        k_dinv_selfloop<<<node_grid, BLK, 0, stream>>>(x, degc, ldinv, s, N_NODES);
        k_scatter_s<<<edge_grid, BLK, 0, stream>>>(src, dst, x, ldinv, s, N_EDGES);
        k_node_g<<<node_grid, BLK, 0, stream>>>(s, ldinv, W1, b1, W2, b2, t, out, N_NODES);
        k_scatter_out<<<edge_grid, BLK, 0, stream>>>(src, dst, ldinv, t, out, N_EDGES);
    }
}